// Round 1
// baseline (433.353 us; speedup 1.0000x reference)
//
#include <hip/hip_runtime.h>

typedef unsigned short ushortT;
typedef unsigned short ushort8 __attribute__((ext_vector_type(8)));
typedef unsigned short ushort4v __attribute__((ext_vector_type(4)));
typedef short short8 __attribute__((ext_vector_type(8)));
typedef float floatx4 __attribute__((ext_vector_type(4)));

#define DEVINL __device__ __forceinline__

static DEVINL ushortT f2bf(float f) {
  union { float f; unsigned u; } v; v.f = f;
  unsigned u = v.u + 0x7FFFu + ((v.u >> 16) & 1u);
  return (ushortT)(u >> 16);
}
static DEVINL float bf2f(ushortT h) {
  union { unsigned u; float f; } v; v.u = ((unsigned)h) << 16;
  return v.f;
}

// dims
// B=16, C=256, HID=512, NH=8, DH=64, N=4096 (64*64), O3=1536
#define NB 16
#define CIN 256
#define HID 512
#define NPIX 4096

// ---------------- K0: convert weights to bf16 ----------------
__global__ __launch_bounds__(256) void k_convw(const float* __restrict__ wqkv,
                                               const float* __restrict__ wout,
                                               ushortT* __restrict__ wqkvb,
                                               ushortT* __restrict__ woutb) {
  int i = blockIdx.x * 256 + threadIdx.x;
  if (i < 1536 * 256) wqkvb[i] = f2bf(wqkv[i]);
  if (i < 256 * 512)  woutb[i] = f2bf(wout[i]);
}

// ---------------- K1: rmsnorm over channels, write xn transposed [b][p][c] bf16 ----------------
__global__ __launch_bounds__(256) void k_rms1(const float* __restrict__ x,
                                              const float* __restrict__ g1,
                                              ushortT* __restrict__ xnT) {
  int pid = blockIdx.x * 256 + threadIdx.x;   // 0..65535
  int b = pid >> 12, p = pid & 4095;
  const float* xb = x + (size_t)b * CIN * NPIX + p;
  float ss = 0.f;
  for (int c = 0; c < CIN; ++c) { float v = xb[(size_t)c * NPIX]; ss += v * v; }
  float nrm = sqrtf(ss);
  float sc = 16.0f / fmaxf(nrm, 1e-12f);
  ushortT* dst = xnT + (size_t)pid * CIN;
  for (int c0 = 0; c0 < CIN; c0 += 8) {
    ushort8 pack;
#pragma unroll
    for (int j = 0; j < 8; ++j) {
      int c = c0 + j;
      pack[j] = f2bf(xb[(size_t)c * NPIX] * sc * g1[c]);
    }
    *(ushort8*)(dst + c0) = pack;
  }
}

// ---------------- K2: qkv GEMM. A=WqkvB [o][c] K-major, B=xnT [p][c] K-major ----------------
// writes q (o<512) transposed to qT[b][p][o]; k,v (o>=512) to kv[b][o-512][p]
__global__ __launch_bounds__(256) void k_qkv(const ushortT* __restrict__ wq,
                                             const ushortT* __restrict__ xnT,
                                             ushortT* __restrict__ qT,
                                             ushortT* __restrict__ kv) {
  int bn = blockIdx.x;       // 0..31  (p tile of 128)
  int bm = blockIdx.y;       // 0..11  (o tile of 128)
  int b  = blockIdx.z;
  int tid = threadIdx.x;
  int w = tid >> 6, l = tid & 63;
  int wm = w >> 1, wn = w & 1;
  int lane_r = l & 15, lane_g = l >> 4;

  const ushortT* xb = xnT + (size_t)b * NPIX * CIN;
  int m0 = bm * 128 + wm * 64;
  int n0 = bn * 128 + wn * 64;

  floatx4 acc[4][4];
#pragma unroll
  for (int i = 0; i < 4; i++)
#pragma unroll
    for (int j = 0; j < 4; j++) acc[i][j] = (floatx4)0.f;

  for (int ks = 0; ks < 8; ++ks) {
    int k0 = ks * 32 + lane_g * 8;
    short8 a[4], bb[4];
#pragma unroll
    for (int mt = 0; mt < 4; ++mt)
      a[mt] = *(const short8*)(wq + (size_t)(m0 + mt * 16 + lane_r) * CIN + k0);
#pragma unroll
    for (int nt = 0; nt < 4; ++nt)
      bb[nt] = *(const short8*)(xb + (size_t)(n0 + nt * 16 + lane_r) * CIN + k0);
#pragma unroll
    for (int mt = 0; mt < 4; ++mt)
#pragma unroll
      for (int nt = 0; nt < 4; ++nt)
        acc[mt][nt] = __builtin_amdgcn_mfma_f32_16x16x32_bf16(a[mt], bb[nt], acc[mt][nt], 0, 0, 0);
  }

  if (m0 < 512) {   // q part -> transposed store qT[p][o], pack 4 consecutive o
    ushortT* qb = qT + (size_t)b * NPIX * HID;
#pragma unroll
    for (int mt = 0; mt < 4; ++mt) {
      int o = m0 + mt * 16 + lane_g * 4;
#pragma unroll
      for (int nt = 0; nt < 4; ++nt) {
        int p = n0 + nt * 16 + lane_r;
        ushort4v pk;
#pragma unroll
        for (int r = 0; r < 4; ++r) pk[r] = f2bf(acc[mt][nt][r]);
        *(ushort4v*)(qb + (size_t)p * HID + o) = pk;
      }
    }
  } else {          // k,v part -> kv[ch][p]
    ushortT* kvb = kv + (size_t)b * 1024 * NPIX;
    int mo = m0 - 512;
#pragma unroll
    for (int mt = 0; mt < 4; ++mt)
#pragma unroll
      for (int nt = 0; nt < 4; ++nt) {
        int p = n0 + nt * 16 + lane_r;
#pragma unroll
        for (int r = 0; r < 4; ++r) {
          int ch = mo + mt * 16 + lane_g * 4 + r;
          kvb[(size_t)ch * NPIX + p] = f2bf(acc[mt][nt][r]);
        }
      }
  }
}

// ---------------- K3a: k softmax over n (4096), in place on kv channels [0,512) ----------------
__global__ __launch_bounds__(256) void k_ksm(ushortT* __restrict__ kv) {
  int row = blockIdx.x;                // 0..8191
  int b = row >> 9, ch = row & 511;
  ushortT* ptr = kv + (size_t)(b * 1024 + ch) * NPIX;
  int tid = threadIdx.x;
  int w = tid >> 6, l = tid & 63;
  float v[16];
  float mx = -1e30f;
#pragma unroll
  for (int j = 0; j < 16; ++j) { v[j] = bf2f(ptr[tid + j * 256]); mx = fmaxf(mx, v[j]); }
  for (int off = 32; off; off >>= 1) mx = fmaxf(mx, __shfl_xor(mx, off));
  __shared__ float smax[4], ssum[4];
  if (l == 0) smax[w] = mx;
  __syncthreads();
  mx = fmaxf(fmaxf(smax[0], smax[1]), fmaxf(smax[2], smax[3]));
  float s = 0.f;
#pragma unroll
  for (int j = 0; j < 16; ++j) { v[j] = __expf(v[j] - mx); s += v[j]; }
  for (int off = 32; off; off >>= 1) s += __shfl_xor(s, off);
  if (l == 0) ssum[w] = s;
  __syncthreads();
  s = ssum[0] + ssum[1] + ssum[2] + ssum[3];
  float inv = 1.0f / s;
#pragma unroll
  for (int j = 0; j < 16; ++j) ptr[tid + j * 256] = f2bf(v[j] * inv);
}

// ---------------- K3b: q softmax over d (64 per head), in place on qT[b][p][hd], *SCALE ----------------
__global__ __launch_bounds__(256) void k_qsm(ushortT* __restrict__ qT) {
  int pid = blockIdx.x * 256 + threadIdx.x;  // 0..65535
  ushortT* ptr = qT + (size_t)pid * HID;
#pragma unroll 1
  for (int h = 0; h < 8; ++h) {
    ushort8 raw[8];
    float v[64];
    float mx = -1e30f;
#pragma unroll
    for (int j = 0; j < 8; ++j) raw[j] = *(ushort8*)(ptr + h * 64 + j * 8);
#pragma unroll
    for (int j = 0; j < 64; ++j) { v[j] = bf2f(raw[j >> 3][j & 7]); mx = fmaxf(mx, v[j]); }
    float s = 0.f;
#pragma unroll
    for (int j = 0; j < 64; ++j) { v[j] = __expf(v[j] - mx); s += v[j]; }
    float inv = 0.125f / s;   // SCALE = DIM_HEAD^-0.5 = 1/8
#pragma unroll
    for (int j = 0; j < 8; ++j) {
      ushort8 pk;
#pragma unroll
      for (int q = 0; q < 8; ++q) pk[q] = f2bf(v[j * 8 + q] * inv);
      *(ushort8*)(ptr + h * 64 + j * 8) = pk;
    }
  }
}

// ---------------- K4: context[d][e] = sum_n k'[d][n] v[e][n], per (b,h) ----------------
__global__ __launch_bounds__(256) void k_ctx(const ushortT* __restrict__ kv,
                                             ushortT* __restrict__ ctx) {
  int bh = blockIdx.x;   // 0..127
  int b = bh >> 3, h = bh & 7;
  int tid = threadIdx.x, w = tid >> 6, l = tid & 63;
  int lane_r = l & 15, lane_g = l >> 4;
  const ushortT* kb = kv + ((size_t)b * 1024 + h * 64) * NPIX;
  const ushortT* vb = kv + ((size_t)b * 1024 + 512 + h * 64) * NPIX;

  floatx4 acc[4][4];
#pragma unroll
  for (int i = 0; i < 4; i++)
#pragma unroll
    for (int j = 0; j < 4; j++) acc[i][j] = (floatx4)0.f;

  for (int ks = 0; ks < 32; ++ks) {
    int k0 = w * 1024 + ks * 32 + lane_g * 8;
    short8 a[4], bb[4];
#pragma unroll
    for (int mt = 0; mt < 4; ++mt) a[mt] = *(const short8*)(kb + (size_t)(mt * 16 + lane_r) * NPIX + k0);
#pragma unroll
    for (int nt = 0; nt < 4; ++nt) bb[nt] = *(const short8*)(vb + (size_t)(nt * 16 + lane_r) * NPIX + k0);
#pragma unroll
    for (int mt = 0; mt < 4; ++mt)
#pragma unroll
      for (int nt = 0; nt < 4; ++nt)
        acc[mt][nt] = __builtin_amdgcn_mfma_f32_16x16x32_bf16(a[mt], bb[nt], acc[mt][nt], 0, 0, 0);
  }
  __shared__ float red[4][64][64];
#pragma unroll
  for (int mt = 0; mt < 4; ++mt)
#pragma unroll
    for (int nt = 0; nt < 4; ++nt)
#pragma unroll
      for (int r = 0; r < 4; ++r)
        red[w][mt * 16 + lane_g * 4 + r][nt * 16 + lane_r] = acc[mt][nt][r];
  __syncthreads();
  ushortT* cb = ctx + (size_t)bh * 64 * 64;
  int base = tid * 16;
  int d = base >> 6, e0 = base & 63;
#pragma unroll
  for (int j = 0; j < 16; ++j) {
    float s = red[0][d][e0 + j] + red[1][d][e0 + j] + red[2][d][e0 + j] + red[3][d][e0 + j];
    cb[base + j] = f2bf(s);
  }
}

// ---------------- K5: Weff[b][o][h*64+d] = sum_e Wout[o][h*64+e] * ctx[b,h,d,e] ----------------
__global__ __launch_bounds__(256) void k_weff(const ushortT* __restrict__ woutb,
                                              const ushortT* __restrict__ ctx,
                                              ushortT* __restrict__ weff) {
  int bh = blockIdx.x; int b = bh >> 3, h = bh & 7;
  int tid = threadIdx.x, w = tid >> 6, l = tid & 63;
  int lane_r = l & 15, lane_g = l >> 4;
  const ushortT* cb = ctx + (size_t)bh * 64 * 64;

  floatx4 acc[4][4];
#pragma unroll
  for (int i = 0; i < 4; i++)
#pragma unroll
    for (int j = 0; j < 4; j++) acc[i][j] = (floatx4)0.f;

#pragma unroll
  for (int ks = 0; ks < 2; ++ks) {
    int k0 = ks * 32 + lane_g * 8;
    short8 a[4], bb[4];
#pragma unroll
    for (int mt = 0; mt < 4; ++mt)
      a[mt] = *(const short8*)(woutb + (size_t)(w * 64 + mt * 16 + lane_r) * HID + h * 64 + k0);
#pragma unroll
    for (int nt = 0; nt < 4; ++nt)
      bb[nt] = *(const short8*)(cb + (size_t)(nt * 16 + lane_r) * 64 + k0);
#pragma unroll
    for (int mt = 0; mt < 4; ++mt)
#pragma unroll
      for (int nt = 0; nt < 4; ++nt)
        acc[mt][nt] = __builtin_amdgcn_mfma_f32_16x16x32_bf16(a[mt], bb[nt], acc[mt][nt], 0, 0, 0);
  }
  ushortT* wb = weff + (size_t)b * 256 * 512;
#pragma unroll
  for (int mt = 0; mt < 4; ++mt)
#pragma unroll
    for (int nt = 0; nt < 4; ++nt)
#pragma unroll
      for (int r = 0; r < 4; ++r) {
        int o = w * 64 + mt * 16 + lane_g * 4 + r;
        int d = nt * 16 + lane_r;
        wb[(size_t)o * 512 + h * 64 + d] = f2bf(acc[mt][nt][r]);
      }
}

// ---------------- K6: out = Weff[b] @ qT[b]^T, + bias, fused rmsnorm over o ----------------
__global__ __launch_bounds__(256) void k_out(const ushortT* __restrict__ weff,
                                             const ushortT* __restrict__ qT,
                                             const float* __restrict__ bout,
                                             const float* __restrict__ g2,
                                             float* __restrict__ out) {
  int bn = blockIdx.x;   // 0..63 (p tile of 64)
  int b  = blockIdx.y;
  int tid = threadIdx.x, w = tid >> 6, l = tid & 63;
  int lane_r = l & 15, lane_g = l >> 4;
  const ushortT* wb = weff + (size_t)b * 256 * 512;
  const ushortT* qb = qT + (size_t)b * NPIX * HID;
  int n0 = bn * 64;

  floatx4 acc[4][4];
#pragma unroll
  for (int i = 0; i < 4; i++)
#pragma unroll
    for (int j = 0; j < 4; j++) acc[i][j] = (floatx4)0.f;

  for (int ks = 0; ks < 16; ++ks) {
    int k0 = ks * 32 + lane_g * 8;
    short8 a[4], bb[4];
#pragma unroll
    for (int mt = 0; mt < 4; ++mt)
      a[mt] = *(const short8*)(wb + (size_t)(w * 64 + mt * 16 + lane_r) * HID + k0);
#pragma unroll
    for (int nt = 0; nt < 4; ++nt)
      bb[nt] = *(const short8*)(qb + (size_t)(n0 + nt * 16 + lane_r) * HID + k0);
#pragma unroll
    for (int mt = 0; mt < 4; ++mt)
#pragma unroll
      for (int nt = 0; nt < 4; ++nt)
        acc[mt][nt] = __builtin_amdgcn_mfma_f32_16x16x32_bf16(a[mt], bb[nt], acc[mt][nt], 0, 0, 0);
  }

  // bias + per-column (pixel) sum of squares over all 256 rows
  float colsq[4] = {0.f, 0.f, 0.f, 0.f};
#pragma unroll
  for (int mt = 0; mt < 4; ++mt)
#pragma unroll
    for (int r = 0; r < 4; ++r) {
      int o = w * 64 + mt * 16 + lane_g * 4 + r;
      float bo = bout[o];
#pragma unroll
      for (int nt = 0; nt < 4; ++nt) {
        float t = acc[mt][nt][r] + bo;
        acc[mt][nt][r] = t;
        colsq[nt] += t * t;
      }
    }
  // reduce across the 4 lane-groups sharing a column
#pragma unroll
  for (int nt = 0; nt < 4; ++nt) {
    colsq[nt] += __shfl_xor(colsq[nt], 16);
    colsq[nt] += __shfl_xor(colsq[nt], 32);
  }
  __shared__ float cred[4][64];
  if (l < 16) {
#pragma unroll
    for (int nt = 0; nt < 4; ++nt) cred[w][nt * 16 + l] = colsq[nt];
  }
  __syncthreads();
  float inv[4];
#pragma unroll
  for (int nt = 0; nt < 4; ++nt) {
    int col = nt * 16 + lane_r;
    float s = cred[0][col] + cred[1][col] + cred[2][col] + cred[3][col];
    float nrm = sqrtf(s);
    inv[nt] = 16.0f / fmaxf(nrm, 1e-12f);
  }
  float* ob = out + (size_t)b * 256 * NPIX;
#pragma unroll
  for (int mt = 0; mt < 4; ++mt)
#pragma unroll
    for (int r = 0; r < 4; ++r) {
      int o = w * 64 + mt * 16 + lane_g * 4 + r;
      float g = g2[o];
#pragma unroll
      for (int nt = 0; nt < 4; ++nt) {
        int p = n0 + nt * 16 + lane_r;
        ob[(size_t)o * NPIX + p] = acc[mt][nt][r] * inv[nt] * g;
      }
    }
}

extern "C" void kernel_launch(void* const* d_in, const int* in_sizes, int n_in,
                              void* d_out, int out_size, void* d_ws, size_t ws_size,
                              hipStream_t stream) {
  const float* x    = (const float*)d_in[0];
  const float* g1   = (const float*)d_in[1];
  const float* wqkv = (const float*)d_in[2];
  const float* wout = (const float*)d_in[3];
  const float* bout = (const float*)d_in[4];
  const float* g2   = (const float*)d_in[5];
  float* out = (float*)d_out;
  char* ws = (char*)d_ws;

  // workspace layout (bytes)
  ushortT* xnT   = (ushortT*)(ws);                       // 16*4096*256*2  = 33554432
  ushortT* kv    = (ushortT*)(ws + 33554432);            // 16*1024*4096*2 = 134217728
  ushortT* qT    = (ushortT*)(ws + 167772160);           // 16*4096*512*2  = 67108864
  ushortT* ctx   = (ushortT*)(ws + 234881024);           // 16*8*64*64*2   = 131072
  ushortT* weff  = (ushortT*)(ws + 235012096);           // 16*256*512*2   = 4194304
  ushortT* wqkvb = (ushortT*)(ws + 239206400);           // 1536*256*2     = 786432
  ushortT* woutb = (ushortT*)(ws + 239992832);           // 256*512*2      = 262144

  hipLaunchKernelGGL(k_convw, dim3(1536), dim3(256), 0, stream, wqkv, wout, wqkvb, woutb);
  hipLaunchKernelGGL(k_rms1,  dim3(256),  dim3(256), 0, stream, x, g1, xnT);
  hipLaunchKernelGGL(k_qkv,   dim3(32, 12, 16), dim3(256), 0, stream, wqkvb, xnT, qT, kv);
  hipLaunchKernelGGL(k_ksm,   dim3(8192), dim3(256), 0, stream, kv);
  hipLaunchKernelGGL(k_qsm,   dim3(256),  dim3(256), 0, stream, qT);
  hipLaunchKernelGGL(k_ctx,   dim3(128),  dim3(256), 0, stream, kv, ctx);
  hipLaunchKernelGGL(k_weff,  dim3(128),  dim3(256), 0, stream, woutb, ctx, weff);
  hipLaunchKernelGGL(k_out,   dim3(64, 16), dim3(256), 0, stream, weff, qT, bout, g2, out);
}

// Round 2
// 279.967 us; speedup vs baseline: 1.5479x; 1.5479x over previous
//
#include <hip/hip_runtime.h>

typedef unsigned short ushortT;
typedef unsigned short ushort8 __attribute__((ext_vector_type(8)));
typedef unsigned short ushort4v __attribute__((ext_vector_type(4)));
typedef short short8 __attribute__((ext_vector_type(8)));
typedef float floatx4 __attribute__((ext_vector_type(4)));

#define DEVINL __device__ __forceinline__

static DEVINL ushortT f2bf(float f) {
  union { float f; unsigned u; } v; v.f = f;
  unsigned u = v.u + 0x7FFFu + ((v.u >> 16) & 1u);
  return (ushortT)(u >> 16);
}
static DEVINL float bf2f(ushortT h) {
  union { unsigned u; float f; } v; v.u = ((unsigned)h) << 16;
  return v.f;
}

#define GLOAD_LDS16(g, s) __builtin_amdgcn_global_load_lds( \
    (const __attribute__((address_space(1))) void*)(g),     \
    (__attribute__((address_space(3))) void*)(s), 16, 0, 0)

// dims: B=16, C=256, HID=512, NH=8, DH=64, N=4096
#define NB 16
#define CIN 256
#define HID 512
#define NPIX 4096

// ---------------- K0: convert weights to bf16 ----------------
__global__ __launch_bounds__(256) void k_convw(const float* __restrict__ wqkv,
                                               const float* __restrict__ wout,
                                               ushortT* __restrict__ wqkvb,
                                               ushortT* __restrict__ woutb) {
  int i = blockIdx.x * 256 + threadIdx.x;
  if (i < 1536 * 256) wqkvb[i] = f2bf(wqkv[i]);
  if (i < 256 * 512)  woutb[i] = f2bf(wout[i]);
}

// ---------------- K1: rmsnorm over channels, write xn transposed [b][p][c] bf16 ----------------
__global__ __launch_bounds__(256) void k_rms1(const float* __restrict__ x,
                                              const float* __restrict__ g1,
                                              ushortT* __restrict__ xnT) {
  int pid = blockIdx.x * 256 + threadIdx.x;   // 0..65535
  int b = pid >> 12, p = pid & 4095;
  const float* xb = x + (size_t)b * CIN * NPIX + p;
  float ss = 0.f;
  for (int c = 0; c < CIN; ++c) { float v = xb[(size_t)c * NPIX]; ss += v * v; }
  float nrm = sqrtf(ss);
  float sc = 16.0f / fmaxf(nrm, 1e-12f);
  ushortT* dst = xnT + (size_t)pid * CIN;
  for (int c0 = 0; c0 < CIN; c0 += 8) {
    ushort8 pack;
#pragma unroll
    for (int j = 0; j < 8; ++j) {
      int c = c0 + j;
      pack[j] = f2bf(xb[(size_t)c * NPIX] * sc * g1[c]);
    }
    *(ushort8*)(dst + c0) = pack;
  }
}

// ---------------- K2: qkv GEMM, m97-style LDS staging via global_load_lds ----------------
// A=WqkvB [o][c] K-major, B=xnT [p][c] K-major.
// q (o<512): fused softmax over d (wave-local 64 rows = one head) -> qT[b][p][o]
// k,v (o>=512): kv[b][o-512][p]
__global__ __launch_bounds__(256) void k_qkv(const ushortT* __restrict__ wq,
                                             const ushortT* __restrict__ xnT,
                                             ushortT* __restrict__ qT,
                                             ushortT* __restrict__ kv) {
  int bn = blockIdx.x;       // 0..31  (p tile of 128)
  int bm = blockIdx.y;       // 0..11  (o tile of 128)
  int b  = blockIdx.z;
  int tid = threadIdx.x;
  int w = tid >> 6, l = tid & 63;
  int wm = w >> 1, wn = w & 1;
  int lane_r = l & 15, lane_g = l >> 4;
  int m0 = bm * 128, n0 = bn * 128;

  __shared__ ushortT As[128 * 32];   // [row][32] bf16, 64B rows, 8KB
  __shared__ ushortT Bs[128 * 32];

  const ushortT* xb = xnT + (size_t)b * NPIX * CIN;

  int r4 = tid >> 2;             // staging row 0..63
  int c8 = (tid & 3) * 8;        // staging col (bf16 units)

  floatx4 acc[4][4];
#pragma unroll
  for (int i = 0; i < 4; i++)
#pragma unroll
    for (int j = 0; j < 4; j++) acc[i][j] = (floatx4)0.f;

  for (int ks = 0; ks < 8; ++ks) {
    int k0 = ks * 32;
    const ushortT* gA = wq + (size_t)(m0 + r4) * CIN + k0 + c8;
    const ushortT* gB = xb + (size_t)(n0 + r4) * CIN + k0 + c8;
    ushortT* sA = As + w * 512;    // wave-uniform LDS base (1KB per wave slice)
    ushortT* sB = Bs + w * 512;
    if (ks) __syncthreads();       // previous iter's ds_reads done before overwrite
    GLOAD_LDS16(gA,            sA);
    GLOAD_LDS16(gA + 64 * CIN, sA + 2048);
    GLOAD_LDS16(gB,            sB);
    GLOAD_LDS16(gB + 64 * CIN, sB + 2048);
    __syncthreads();               // vmcnt(0) drained by compiler before barrier

    short8 a[4], bb[4];
#pragma unroll
    for (int mt = 0; mt < 4; ++mt)
      a[mt] = *(const short8*)&As[(wm * 64 + mt * 16 + lane_r) * 32 + lane_g * 8];
#pragma unroll
    for (int nt = 0; nt < 4; ++nt)
      bb[nt] = *(const short8*)&Bs[(wn * 64 + nt * 16 + lane_r) * 32 + lane_g * 8];
#pragma unroll
    for (int mt = 0; mt < 4; ++mt)
#pragma unroll
      for (int nt = 0; nt < 4; ++nt)
        acc[mt][nt] = __builtin_amdgcn_mfma_f32_16x16x32_bf16(a[mt], bb[nt], acc[mt][nt], 0, 0, 0);
  }

  int m0w = m0 + wm * 64, n0w = n0 + wn * 64;

  if (m0w < 512) {
    // ---- fused q softmax over d: wave's 64 rows are exactly one head ----
    float inv[4];
#pragma unroll
    for (int nt = 0; nt < 4; ++nt) {
      float mx = -1e30f;
#pragma unroll
      for (int mt = 0; mt < 4; ++mt)
#pragma unroll
        for (int r = 0; r < 4; ++r) mx = fmaxf(mx, acc[mt][nt][r]);
      mx = fmaxf(mx, __shfl_xor(mx, 16));
      mx = fmaxf(mx, __shfl_xor(mx, 32));
      float s = 0.f;
#pragma unroll
      for (int mt = 0; mt < 4; ++mt)
#pragma unroll
        for (int r = 0; r < 4; ++r) {
          float e = __expf(acc[mt][nt][r] - mx);
          acc[mt][nt][r] = e;
          s += e;
        }
      s += __shfl_xor(s, 16);
      s += __shfl_xor(s, 32);
      inv[nt] = 0.125f / s;    // SCALE = 1/8 folded in
    }
    ushortT* qb = qT + (size_t)b * NPIX * HID;
#pragma unroll
    for (int mt = 0; mt < 4; ++mt) {
      int o = m0w + mt * 16 + lane_g * 4;
#pragma unroll
      for (int nt = 0; nt < 4; ++nt) {
        int p = n0w + nt * 16 + lane_r;
        ushort4v pk;
#pragma unroll
        for (int r = 0; r < 4; ++r) pk[r] = f2bf(acc[mt][nt][r] * inv[nt]);
        *(ushort4v*)(qb + (size_t)p * HID + o) = pk;
      }
    }
  } else {          // k,v part -> kv[ch][p]
    ushortT* kvb = kv + (size_t)b * 1024 * NPIX;
    int mo = m0w - 512;
#pragma unroll
    for (int mt = 0; mt < 4; ++mt)
#pragma unroll
      for (int nt = 0; nt < 4; ++nt) {
        int p = n0w + nt * 16 + lane_r;
#pragma unroll
        for (int r = 0; r < 4; ++r) {
          int ch = mo + mt * 16 + lane_g * 4 + r;
          kvb[(size_t)ch * NPIX + p] = f2bf(acc[mt][nt][r]);
        }
      }
  }
}

// ---------------- K3a: k softmax over n (4096), in place on kv channels [0,512) ----------------
__global__ __launch_bounds__(256) void k_ksm(ushortT* __restrict__ kv) {
  int row = blockIdx.x;                // 0..8191
  int b = row >> 9, ch = row & 511;
  ushortT* ptr = kv + (size_t)(b * 1024 + ch) * NPIX;
  int tid = threadIdx.x;
  int w = tid >> 6, l = tid & 63;
  float v[16];
  float mx = -1e30f;
#pragma unroll
  for (int j = 0; j < 16; ++j) { v[j] = bf2f(ptr[tid + j * 256]); mx = fmaxf(mx, v[j]); }
  for (int off = 32; off; off >>= 1) mx = fmaxf(mx, __shfl_xor(mx, off));
  __shared__ float smax[4], ssum[4];
  if (l == 0) smax[w] = mx;
  __syncthreads();
  mx = fmaxf(fmaxf(smax[0], smax[1]), fmaxf(smax[2], smax[3]));
  float s = 0.f;
#pragma unroll
  for (int j = 0; j < 16; ++j) { v[j] = __expf(v[j] - mx); s += v[j]; }
  for (int off = 32; off; off >>= 1) s += __shfl_xor(s, off);
  if (l == 0) ssum[w] = s;
  __syncthreads();
  s = ssum[0] + ssum[1] + ssum[2] + ssum[3];
  float inv = 1.0f / s;
#pragma unroll
  for (int j = 0; j < 16; ++j) ptr[tid + j * 256] = f2bf(v[j] * inv);
}

// ---------------- K4: partial context over n-segment: ctxp[bh*4+ns][d][e] ----------------
__global__ __launch_bounds__(256) void k_ctx(const ushortT* __restrict__ kv,
                                             float* __restrict__ ctxp) {
  int blk = blockIdx.x;   // 0..511
  int bh = blk >> 2, ns = blk & 3;
  int b = bh >> 3, h = bh & 7;
  int tid = threadIdx.x, w = tid >> 6, l = tid & 63;
  int lane_r = l & 15, lane_g = l >> 4;
  const ushortT* kb = kv + ((size_t)b * 1024 + h * 64) * NPIX;
  const ushortT* vb = kv + ((size_t)b * 1024 + 512 + h * 64) * NPIX;

  floatx4 acc[4][4];
#pragma unroll
  for (int i = 0; i < 4; i++)
#pragma unroll
    for (int j = 0; j < 4; j++) acc[i][j] = (floatx4)0.f;

  for (int ks = 0; ks < 8; ++ks) {
    int k0 = ns * 1024 + w * 256 + ks * 32 + lane_g * 8;
    short8 a[4], bb[4];
#pragma unroll
    for (int mt = 0; mt < 4; ++mt) a[mt] = *(const short8*)(kb + (size_t)(mt * 16 + lane_r) * NPIX + k0);
#pragma unroll
    for (int nt = 0; nt < 4; ++nt) bb[nt] = *(const short8*)(vb + (size_t)(nt * 16 + lane_r) * NPIX + k0);
#pragma unroll
    for (int mt = 0; mt < 4; ++mt)
#pragma unroll
      for (int nt = 0; nt < 4; ++nt)
        acc[mt][nt] = __builtin_amdgcn_mfma_f32_16x16x32_bf16(a[mt], bb[nt], acc[mt][nt], 0, 0, 0);
  }
  __shared__ float red[4][64][64];
#pragma unroll
  for (int mt = 0; mt < 4; ++mt)
#pragma unroll
    for (int nt = 0; nt < 4; ++nt)
#pragma unroll
      for (int r = 0; r < 4; ++r)
        red[w][mt * 16 + lane_g * 4 + r][nt * 16 + lane_r] = acc[mt][nt][r];
  __syncthreads();
  float* cb = ctxp + (size_t)blk * 4096;
  int base = tid * 16;
  int d = base >> 6, e0 = base & 63;
#pragma unroll
  for (int j = 0; j < 16; ++j)
    cb[base + j] = red[0][d][e0 + j] + red[1][d][e0 + j] + red[2][d][e0 + j] + red[3][d][e0 + j];
}

// ---------------- K4b: sum 4 n-segment partials -> ctx bf16 ----------------
__global__ __launch_bounds__(256) void k_ctxsum(const float* __restrict__ ctxp,
                                                ushortT* __restrict__ ctx) {
  int i = blockIdx.x * 256 + threadIdx.x;   // < 524288
  int bh = i >> 12, j = i & 4095;
  const float* p = ctxp + (size_t)bh * 4 * 4096 + j;
  ctx[i] = f2bf(p[0] + p[4096] + p[8192] + p[12288]);
}

// ---------------- K5: Weff[b][o][h*64+d] = sum_e Wout[o][h*64+e] * ctx[b,h,d,e] ----------------
__global__ __launch_bounds__(256) void k_weff(const ushortT* __restrict__ woutb,
                                              const ushortT* __restrict__ ctx,
                                              ushortT* __restrict__ weff) {
  int bh = blockIdx.x; int b = bh >> 3, h = bh & 7;
  int tid = threadIdx.x, w = tid >> 6, l = tid & 63;
  int lane_r = l & 15, lane_g = l >> 4;
  const ushortT* cb = ctx + (size_t)bh * 64 * 64;

  floatx4 acc[4][4];
#pragma unroll
  for (int i = 0; i < 4; i++)
#pragma unroll
    for (int j = 0; j < 4; j++) acc[i][j] = (floatx4)0.f;

#pragma unroll
  for (int ks = 0; ks < 2; ++ks) {
    int k0 = ks * 32 + lane_g * 8;
    short8 a[4], bb[4];
#pragma unroll
    for (int mt = 0; mt < 4; ++mt)
      a[mt] = *(const short8*)(woutb + (size_t)(w * 64 + mt * 16 + lane_r) * HID + h * 64 + k0);
#pragma unroll
    for (int nt = 0; nt < 4; ++nt)
      bb[nt] = *(const short8*)(cb + (size_t)(nt * 16 + lane_r) * 64 + k0);
#pragma unroll
    for (int mt = 0; mt < 4; ++mt)
#pragma unroll
      for (int nt = 0; nt < 4; ++nt)
        acc[mt][nt] = __builtin_amdgcn_mfma_f32_16x16x32_bf16(a[mt], bb[nt], acc[mt][nt], 0, 0, 0);
  }
  ushortT* wb = weff + (size_t)b * 256 * 512;
#pragma unroll
  for (int mt = 0; mt < 4; ++mt)
#pragma unroll
    for (int nt = 0; nt < 4; ++nt)
#pragma unroll
      for (int r = 0; r < 4; ++r) {
        int o = w * 64 + mt * 16 + lane_g * 4 + r;
        int d = nt * 16 + lane_r;
        wb[(size_t)o * 512 + h * 64 + d] = f2bf(acc[mt][nt][r]);
      }
}

// ---------------- K6: out = Weff[b] @ qT[b]^T, + bias, fused rmsnorm over o ----------------
__global__ __launch_bounds__(256) void k_out(const ushortT* __restrict__ weff,
                                             const ushortT* __restrict__ qT,
                                             const float* __restrict__ bout,
                                             const float* __restrict__ g2,
                                             float* __restrict__ out) {
  int bn = blockIdx.x;   // 0..63 (p tile of 64)
  int b  = blockIdx.y;
  int tid = threadIdx.x, w = tid >> 6, l = tid & 63;
  int lane_r = l & 15, lane_g = l >> 4;
  const ushortT* wb = weff + (size_t)b * 256 * 512;
  const ushortT* qb = qT + (size_t)b * NPIX * HID;
  int n0 = bn * 64;

  floatx4 acc[4][4];
#pragma unroll
  for (int i = 0; i < 4; i++)
#pragma unroll
    for (int j = 0; j < 4; j++) acc[i][j] = (floatx4)0.f;

  for (int ks = 0; ks < 16; ++ks) {
    int k0 = ks * 32 + lane_g * 8;
    short8 a[4], bb[4];
#pragma unroll
    for (int mt = 0; mt < 4; ++mt)
      a[mt] = *(const short8*)(wb + (size_t)(w * 64 + mt * 16 + lane_r) * HID + k0);
#pragma unroll
    for (int nt = 0; nt < 4; ++nt)
      bb[nt] = *(const short8*)(qb + (size_t)(n0 + nt * 16 + lane_r) * HID + k0);
#pragma unroll
    for (int mt = 0; mt < 4; ++mt)
#pragma unroll
      for (int nt = 0; nt < 4; ++nt)
        acc[mt][nt] = __builtin_amdgcn_mfma_f32_16x16x32_bf16(a[mt], bb[nt], acc[mt][nt], 0, 0, 0);
  }

  float colsq[4] = {0.f, 0.f, 0.f, 0.f};
#pragma unroll
  for (int mt = 0; mt < 4; ++mt)
#pragma unroll
    for (int r = 0; r < 4; ++r) {
      int o = w * 64 + mt * 16 + lane_g * 4 + r;
      float bo = bout[o];
#pragma unroll
      for (int nt = 0; nt < 4; ++nt) {
        float t = acc[mt][nt][r] + bo;
        acc[mt][nt][r] = t;
        colsq[nt] += t * t;
      }
    }
#pragma unroll
  for (int nt = 0; nt < 4; ++nt) {
    colsq[nt] += __shfl_xor(colsq[nt], 16);
    colsq[nt] += __shfl_xor(colsq[nt], 32);
  }
  __shared__ float cred[4][64];
  if (l < 16) {
#pragma unroll
    for (int nt = 0; nt < 4; ++nt) cred[w][nt * 16 + l] = colsq[nt];
  }
  __syncthreads();
  float inv[4];
#pragma unroll
  for (int nt = 0; nt < 4; ++nt) {
    int col = nt * 16 + lane_r;
    float s = cred[0][col] + cred[1][col] + cred[2][col] + cred[3][col];
    float nrm = sqrtf(s);
    inv[nt] = 16.0f / fmaxf(nrm, 1e-12f);
  }
  float* ob = out + (size_t)b * 256 * NPIX;
#pragma unroll
  for (int mt = 0; mt < 4; ++mt)
#pragma unroll
    for (int r = 0; r < 4; ++r) {
      int o = w * 64 + mt * 16 + lane_g * 4 + r;
      float g = g2[o];
#pragma unroll
      for (int nt = 0; nt < 4; ++nt) {
        int p = n0 + nt * 16 + lane_r;
        ob[(size_t)o * NPIX + p] = acc[mt][nt][r] * inv[nt] * g;
      }
    }
}

extern "C" void kernel_launch(void* const* d_in, const int* in_sizes, int n_in,
                              void* d_out, int out_size, void* d_ws, size_t ws_size,
                              hipStream_t stream) {
  const float* x    = (const float*)d_in[0];
  const float* g1   = (const float*)d_in[1];
  const float* wqkv = (const float*)d_in[2];
  const float* wout = (const float*)d_in[3];
  const float* bout = (const float*)d_in[4];
  const float* g2   = (const float*)d_in[5];
  float* out = (float*)d_out;
  char* ws = (char*)d_ws;

  // workspace layout (bytes)
  ushortT* xnT   = (ushortT*)(ws);                       // 16*4096*256*2  = 33554432
  ushortT* kv    = (ushortT*)(ws + 33554432);            // 16*1024*4096*2 = 134217728
  ushortT* qT    = (ushortT*)(ws + 167772160);           // 16*4096*512*2  = 67108864
  ushortT* ctx   = (ushortT*)(ws + 234881024);           // 16*8*64*64*2   = 131072
  ushortT* weff  = (ushortT*)(ws + 235012096);           // 16*256*512*2   = 4194304
  ushortT* wqkvb = (ushortT*)(ws + 239206400);           // 1536*256*2     = 786432
  ushortT* woutb = (ushortT*)(ws + 239992832);           // 256*512*2      = 262144
  float*   ctxp  = (float*)(ws);                         // 128*4*4096*4 = 8MB, reuses dead xnT region

  hipLaunchKernelGGL(k_convw,  dim3(1536), dim3(256), 0, stream, wqkv, wout, wqkvb, woutb);
  hipLaunchKernelGGL(k_rms1,   dim3(256),  dim3(256), 0, stream, x, g1, xnT);
  hipLaunchKernelGGL(k_qkv,    dim3(32, 12, 16), dim3(256), 0, stream, wqkvb, xnT, qT, kv);
  hipLaunchKernelGGL(k_ksm,    dim3(8192), dim3(256), 0, stream, kv);
  hipLaunchKernelGGL(k_ctx,    dim3(512),  dim3(256), 0, stream, kv, ctxp);
  hipLaunchKernelGGL(k_ctxsum, dim3(2048), dim3(256), 0, stream, ctxp, ctx);
  hipLaunchKernelGGL(k_weff,   dim3(128),  dim3(256), 0, stream, woutb, ctx, weff);
  hipLaunchKernelGGL(k_out,    dim3(64, 16), dim3(256), 0, stream, weff, qT, bout, g2, out);
}

// Round 3
// 246.671 us; speedup vs baseline: 1.7568x; 1.1350x over previous
//
#include <hip/hip_runtime.h>

typedef unsigned short ushortT;
typedef unsigned short ushort8 __attribute__((ext_vector_type(8)));
typedef unsigned short ushort4v __attribute__((ext_vector_type(4)));
typedef short short8 __attribute__((ext_vector_type(8)));
typedef float floatx4 __attribute__((ext_vector_type(4)));

#define DEVINL __device__ __forceinline__

static DEVINL ushortT f2bf(float f) {
  union { float f; unsigned u; } v; v.f = f;
  unsigned u = v.u + 0x7FFFu + ((v.u >> 16) & 1u);
  return (ushortT)(u >> 16);
}
static DEVINL float bf2f(ushortT h) {
  union { unsigned u; float f; } v; v.u = ((unsigned)h) << 16;
  return v.f;
}

#define GLOAD_LDS16(g, s) __builtin_amdgcn_global_load_lds( \
    (const __attribute__((address_space(1))) void*)(g),     \
    (__attribute__((address_space(3))) void*)(s), 16, 0, 0)

// dims: B=16, C=256, HID=512, NH=8, DH=64, N=4096
#define NB 16
#define CIN 256
#define HID 512
#define NPIX 4096

// ---------------- K0: convert weights to bf16 ----------------
__global__ __launch_bounds__(256) void k_convw(const float* __restrict__ wqkv,
                                               const float* __restrict__ wout,
                                               ushortT* __restrict__ wqkvb,
                                               ushortT* __restrict__ woutb) {
  int i = blockIdx.x * 256 + threadIdx.x;
  if (i < 1536 * 256) wqkvb[i] = f2bf(wqkv[i]);
  if (i < 256 * 512)  woutb[i] = f2bf(wout[i]);
}

// ---------------- K1: rmsnorm over channels, write xn transposed [b][p][c] bf16 ----------------
__global__ __launch_bounds__(256) void k_rms1(const float* __restrict__ x,
                                              const float* __restrict__ g1,
                                              ushortT* __restrict__ xnT) {
  int pid = blockIdx.x * 256 + threadIdx.x;   // 0..65535
  int b = pid >> 12, p = pid & 4095;
  const float* xb = x + (size_t)b * CIN * NPIX + p;
  float ss = 0.f;
  for (int c = 0; c < CIN; ++c) { float v = xb[(size_t)c * NPIX]; ss += v * v; }
  float nrm = sqrtf(ss);
  float sc = 16.0f / fmaxf(nrm, 1e-12f);
  ushortT* dst = xnT + (size_t)pid * CIN;
  for (int c0 = 0; c0 < CIN; c0 += 8) {
    ushort8 pack;
#pragma unroll
    for (int j = 0; j < 8; ++j) {
      int c = c0 + j;
      pack[j] = f2bf(xb[(size_t)c * NPIX] * sc * g1[c]);
    }
    *(ushort8*)(dst + c0) = pack;
  }
}

// ---------------- K2: qkv GEMM, swizzled LDS + double-buffered staging ----------------
// A=WqkvB [o][c] K-major, B=xnT [p][c] K-major.
// LDS tile rows are 64B (BK=32): logical 16B chunk g at row R lives at physical
// chunk g ^ ((R>>1)&3)  (2-way bank aliasing = free). Source is pre-swizzled
// since global_load_lds writes linearly (rule: both-sides-or-neither).
__global__ __launch_bounds__(256) void k_qkv(const ushortT* __restrict__ wq,
                                             const ushortT* __restrict__ xnT,
                                             ushortT* __restrict__ qT,
                                             ushortT* __restrict__ kv) {
  int bn = blockIdx.x;       // 0..31  (p tile of 128)
  int bm = blockIdx.y;       // 0..11  (o tile of 128)
  int b  = blockIdx.z;
  int tid = threadIdx.x;
  int w = tid >> 6, l = tid & 63;
  int wm = w >> 1, wn = w & 1;
  int lane_r = l & 15, lane_g = l >> 4;
  int m0 = bm * 128, n0 = bn * 128;

  __shared__ ushortT As[2][128 * 32];   // 8KB per buf
  __shared__ ushortT Bs[2][128 * 32];

  const ushortT* xb = xnT + (size_t)b * NPIX * CIN;

  int srow = tid >> 2;                                // staging row 0..63
  int scol = ((tid & 3) ^ ((tid >> 3) & 3)) * 8;      // pre-swizzled source col (elems)
  const ushortT* gA0 = wq + (size_t)(m0 + srow) * CIN + scol;
  const ushortT* gB0 = xb + (size_t)(n0 + srow) * CIN + scol;
  int wofs = w * 512;                                 // per-wave LDS base (ushorts)
  int rq = (lane_r >> 1) & 3;                         // read-side swizzle term

  floatx4 acc[4][4];
#pragma unroll
  for (int i = 0; i < 4; i++)
#pragma unroll
    for (int j = 0; j < 4; j++) acc[i][j] = (floatx4)0.f;

  // prologue: stage k-step 0 into buf 0
  GLOAD_LDS16(gA0,            &As[0][wofs]);
  GLOAD_LDS16(gA0 + 64 * CIN, &As[0][2048 + wofs]);
  GLOAD_LDS16(gB0,            &Bs[0][wofs]);
  GLOAD_LDS16(gB0 + 64 * CIN, &Bs[0][2048 + wofs]);
  __syncthreads();

  int buf = 0;
  for (int ks = 0; ks < 8; ++ks) {
    if (ks < 7) {
      int k0 = (ks + 1) * 32;
      int nb = buf ^ 1;
      GLOAD_LDS16(gA0 + k0,            &As[nb][wofs]);
      GLOAD_LDS16(gA0 + 64 * CIN + k0, &As[nb][2048 + wofs]);
      GLOAD_LDS16(gB0 + k0,            &Bs[nb][wofs]);
      GLOAD_LDS16(gB0 + 64 * CIN + k0, &Bs[nb][2048 + wofs]);
    }
    short8 a[4], bb[4];
#pragma unroll
    for (int mt = 0; mt < 4; ++mt) {
      int R = wm * 64 + mt * 16 + lane_r;
      a[mt] = *(const short8*)&As[buf][R * 32 + (lane_g ^ rq) * 8];
    }
#pragma unroll
    for (int nt = 0; nt < 4; ++nt) {
      int R = wn * 64 + nt * 16 + lane_r;
      bb[nt] = *(const short8*)&Bs[buf][R * 32 + (lane_g ^ rq) * 8];
    }
#pragma unroll
    for (int mt = 0; mt < 4; ++mt)
#pragma unroll
      for (int nt = 0; nt < 4; ++nt)
        acc[mt][nt] = __builtin_amdgcn_mfma_f32_16x16x32_bf16(a[mt], bb[nt], acc[mt][nt], 0, 0, 0);
    if (ks < 7) __syncthreads();
    buf ^= 1;
  }

  int m0w = m0 + wm * 64, n0w = n0 + wn * 64;

  if (m0w < 512) {
    // ---- fused q softmax over d: wave's 64 rows are exactly one head ----
    float inv[4];
#pragma unroll
    for (int nt = 0; nt < 4; ++nt) {
      float mx = -1e30f;
#pragma unroll
      for (int mt = 0; mt < 4; ++mt)
#pragma unroll
        for (int r = 0; r < 4; ++r) mx = fmaxf(mx, acc[mt][nt][r]);
      mx = fmaxf(mx, __shfl_xor(mx, 16));
      mx = fmaxf(mx, __shfl_xor(mx, 32));
      float s = 0.f;
#pragma unroll
      for (int mt = 0; mt < 4; ++mt)
#pragma unroll
        for (int r = 0; r < 4; ++r) {
          float e = __expf(acc[mt][nt][r] - mx);
          acc[mt][nt][r] = e;
          s += e;
        }
      s += __shfl_xor(s, 16);
      s += __shfl_xor(s, 32);
      inv[nt] = 0.125f / s;    // SCALE = 1/8 folded in
    }
    ushortT* qb = qT + (size_t)b * NPIX * HID;
#pragma unroll
    for (int mt = 0; mt < 4; ++mt) {
      int o = m0w + mt * 16 + lane_g * 4;
#pragma unroll
      for (int nt = 0; nt < 4; ++nt) {
        int p = n0w + nt * 16 + lane_r;
        ushort4v pk;
#pragma unroll
        for (int r = 0; r < 4; ++r) pk[r] = f2bf(acc[mt][nt][r] * inv[nt]);
        *(ushort4v*)(qb + (size_t)p * HID + o) = pk;
      }
    }
  } else {          // k,v part -> kv[ch][p]
    ushortT* kvb = kv + (size_t)b * 1024 * NPIX;
    int mo = m0w - 512;
#pragma unroll
    for (int mt = 0; mt < 4; ++mt)
#pragma unroll
      for (int nt = 0; nt < 4; ++nt) {
        int p = n0w + nt * 16 + lane_r;
#pragma unroll
        for (int r = 0; r < 4; ++r) {
          int ch = mo + mt * 16 + lane_g * 4 + r;
          kvb[(size_t)ch * NPIX + p] = f2bf(acc[mt][nt][r]);
        }
      }
  }
}

// ---------------- K3a: k softmax over n (4096), in place on kv channels [0,512) ----------------
__global__ __launch_bounds__(256) void k_ksm(ushortT* __restrict__ kv) {
  int row = blockIdx.x;                // 0..8191
  int b = row >> 9, ch = row & 511;
  ushortT* ptr = kv + (size_t)(b * 1024 + ch) * NPIX;
  int tid = threadIdx.x;
  int w = tid >> 6, l = tid & 63;
  float v[16];
  float mx = -1e30f;
#pragma unroll
  for (int j = 0; j < 16; ++j) { v[j] = bf2f(ptr[tid + j * 256]); mx = fmaxf(mx, v[j]); }
  for (int off = 32; off; off >>= 1) mx = fmaxf(mx, __shfl_xor(mx, off));
  __shared__ float smax[4], ssum[4];
  if (l == 0) smax[w] = mx;
  __syncthreads();
  mx = fmaxf(fmaxf(smax[0], smax[1]), fmaxf(smax[2], smax[3]));
  float s = 0.f;
#pragma unroll
  for (int j = 0; j < 16; ++j) { v[j] = __expf(v[j] - mx); s += v[j]; }
  for (int off = 32; off; off >>= 1) s += __shfl_xor(s, off);
  if (l == 0) ssum[w] = s;
  __syncthreads();
  s = ssum[0] + ssum[1] + ssum[2] + ssum[3];
  float inv = 1.0f / s;
#pragma unroll
  for (int j = 0; j < 16; ++j) ptr[tid + j * 256] = f2bf(v[j] * inv);
}

// ---------------- K4: partial context over n-segment, staged LDS ----------------
// Tile [64 rows][128 n-cols], 256B rows, 16 chunks of 16B; physical chunk =
// logical ^ (row&15) (2-way = free). Staging ops fetch full 256B per row.
// 4 waves partition the 128 n-cols (n-partition); cross-wave reduce via LDS
// aliased over the staging buffers after the final barrier.
__global__ __launch_bounds__(256) void k_ctx(const ushortT* __restrict__ kv,
                                             float* __restrict__ ctxp) {
  int blk = blockIdx.x;   // 0..511
  int bh = blk >> 2, ns = blk & 3;
  int b = bh >> 3, h = bh & 7;
  int tid = threadIdx.x, w = tid >> 6, l = tid & 63;
  int lane_r = l & 15, lane_g = l >> 4;
  const ushortT* kb = kv + ((size_t)b * 1024 + h * 64) * NPIX + ns * 1024;
  const ushortT* vb = kv + ((size_t)b * 1024 + 512 + h * 64) * NPIX + ns * 1024;

  __shared__ ushortT smem[4][64 * 128];   // 64KB total: [0..1]=K bufs, [2..3]=V bufs

  int srow = tid >> 4;                    // 0..15
  int soff = ((tid & 15) ^ srow) * 8;     // pre-swizzled source col (elems)
  int wofs = w * 512;                     // per-wave LDS base within a 4KB op
  int cbase = (w * 4 + lane_g);           // this wave's logical chunk id

  floatx4 acc[4][4];
#pragma unroll
  for (int i = 0; i < 4; i++)
#pragma unroll
    for (int j = 0; j < 4; j++) acc[i][j] = (floatx4)0.f;

  // prologue stage step 0 into buf 0
#pragma unroll
  for (int i = 0; i < 4; ++i)
    GLOAD_LDS16(kb + (size_t)(srow + 16 * i) * NPIX + soff, &smem[0][i * 2048 + wofs]);
#pragma unroll
  for (int i = 0; i < 4; ++i)
    GLOAD_LDS16(vb + (size_t)(srow + 16 * i) * NPIX + soff, &smem[2][i * 2048 + wofs]);
  __syncthreads();

  int buf = 0;
  for (int st = 0; st < 8; ++st) {
    if (st < 7) {
      int nb0 = (st + 1) * 128;
      int nb = buf ^ 1;
#pragma unroll
      for (int i = 0; i < 4; ++i)
        GLOAD_LDS16(kb + (size_t)(srow + 16 * i) * NPIX + nb0 + soff, &smem[nb][i * 2048 + wofs]);
#pragma unroll
      for (int i = 0; i < 4; ++i)
        GLOAD_LDS16(vb + (size_t)(srow + 16 * i) * NPIX + nb0 + soff, &smem[2 + nb][i * 2048 + wofs]);
    }
    short8 a[4], bb[4];
#pragma unroll
    for (int mt = 0; mt < 4; ++mt) {
      int R = mt * 16 + lane_r;
      a[mt] = *(const short8*)&smem[buf][R * 128 + (cbase ^ lane_r) * 8];
    }
#pragma unroll
    for (int nt = 0; nt < 4; ++nt) {
      int R = nt * 16 + lane_r;
      bb[nt] = *(const short8*)&smem[2 + buf][R * 128 + (cbase ^ lane_r) * 8];
    }
#pragma unroll
    for (int mt = 0; mt < 4; ++mt)
#pragma unroll
      for (int nt = 0; nt < 4; ++nt)
        acc[mt][nt] = __builtin_amdgcn_mfma_f32_16x16x32_bf16(a[mt], bb[nt], acc[mt][nt], 0, 0, 0);
    if (st < 7) __syncthreads();
    buf ^= 1;
  }

  // cross-wave reduction, aliasing the (now dead) staging LDS
  __syncthreads();
  float* red = (float*)&smem[0][0];       // [4][64][64] f32 = 64KB
#pragma unroll
  for (int mt = 0; mt < 4; ++mt)
#pragma unroll
    for (int nt = 0; nt < 4; ++nt)
#pragma unroll
      for (int r = 0; r < 4; ++r)
        red[(w * 64 + mt * 16 + lane_g * 4 + r) * 64 + nt * 16 + lane_r] = acc[mt][nt][r];
  __syncthreads();
  float* cb = ctxp + (size_t)blk * 4096;
  int base = tid * 16;
#pragma unroll
  for (int j = 0; j < 16; ++j) {
    int idx = base + j;
    cb[idx] = red[idx] + red[4096 + idx] + red[8192 + idx] + red[12288 + idx];
  }
}

// ---------------- K4b: sum 4 n-segment partials -> ctx bf16 ----------------
__global__ __launch_bounds__(256) void k_ctxsum(const float* __restrict__ ctxp,
                                                ushortT* __restrict__ ctx) {
  int i = blockIdx.x * 256 + threadIdx.x;   // < 524288
  int bh = i >> 12, j = i & 4095;
  const float* p = ctxp + (size_t)bh * 4 * 4096 + j;
  ctx[i] = f2bf(p[0] + p[4096] + p[8192] + p[12288]);
}

// ---------------- K5: Weff[b][o][h*64+d] = sum_e Wout[o][h*64+e] * ctx[b,h,d,e] ----------------
__global__ __launch_bounds__(256) void k_weff(const ushortT* __restrict__ woutb,
                                              const ushortT* __restrict__ ctx,
                                              ushortT* __restrict__ weff) {
  int bh = blockIdx.x; int b = bh >> 3, h = bh & 7;
  int tid = threadIdx.x, w = tid >> 6, l = tid & 63;
  int lane_r = l & 15, lane_g = l >> 4;
  const ushortT* cb = ctx + (size_t)bh * 64 * 64;

  floatx4 acc[4][4];
#pragma unroll
  for (int i = 0; i < 4; i++)
#pragma unroll
    for (int j = 0; j < 4; j++) acc[i][j] = (floatx4)0.f;

#pragma unroll
  for (int ks = 0; ks < 2; ++ks) {
    int k0 = ks * 32 + lane_g * 8;
    short8 a[4], bb[4];
#pragma unroll
    for (int mt = 0; mt < 4; ++mt)
      a[mt] = *(const short8*)(woutb + (size_t)(w * 64 + mt * 16 + lane_r) * HID + h * 64 + k0);
#pragma unroll
    for (int nt = 0; nt < 4; ++nt)
      bb[nt] = *(const short8*)(cb + (size_t)(nt * 16 + lane_r) * 64 + k0);
#pragma unroll
    for (int mt = 0; mt < 4; ++mt)
#pragma unroll
      for (int nt = 0; nt < 4; ++nt)
        acc[mt][nt] = __builtin_amdgcn_mfma_f32_16x16x32_bf16(a[mt], bb[nt], acc[mt][nt], 0, 0, 0);
  }
  ushortT* wb = weff + (size_t)b * 256 * 512;
#pragma unroll
  for (int mt = 0; mt < 4; ++mt)
#pragma unroll
    for (int nt = 0; nt < 4; ++nt)
#pragma unroll
      for (int r = 0; r < 4; ++r) {
        int o = w * 64 + mt * 16 + lane_g * 4 + r;
        int d = nt * 16 + lane_r;
        wb[(size_t)o * 512 + h * 64 + d] = f2bf(acc[mt][nt][r]);
      }
}

// ---------------- K6: out = Weff[b] @ qT[b]^T, staged LDS, + bias, fused rmsnorm ----------------
__global__ __launch_bounds__(256) void k_out(const ushortT* __restrict__ weff,
                                             const ushortT* __restrict__ qT,
                                             const float* __restrict__ bout,
                                             const float* __restrict__ g2,
                                             float* __restrict__ out) {
  int bn = blockIdx.x;   // 0..63 (p tile of 64)
  int b  = blockIdx.y;
  int tid = threadIdx.x, w = tid >> 6, l = tid & 63;
  int lane_r = l & 15, lane_g = l >> 4;
  const ushortT* wb = weff + (size_t)b * 256 * 512;
  const ushortT* qb = qT + (size_t)b * NPIX * HID;
  int n0 = bn * 64;

  __shared__ ushortT As[2][256 * 32];   // 16KB per buf
  __shared__ ushortT Bq[2][64 * 32];    // 4KB per buf

  int srow = tid >> 2;                                // 0..63
  int scol = ((tid & 3) ^ ((tid >> 3) & 3)) * 8;
  const ushortT* gA0 = wb + (size_t)srow * HID + scol;
  const ushortT* gB0 = qb + (size_t)(n0 + srow) * HID + scol;
  int wofs = w * 512;
  int rq = (lane_r >> 1) & 3;

  floatx4 acc[4][4];
#pragma unroll
  for (int i = 0; i < 4; i++)
#pragma unroll
    for (int j = 0; j < 4; j++) acc[i][j] = (floatx4)0.f;

  // prologue
#pragma unroll
  for (int i = 0; i < 4; ++i)
    GLOAD_LDS16(gA0 + (size_t)(64 * i) * HID, &As[0][i * 2048 + wofs]);
  GLOAD_LDS16(gB0, &Bq[0][wofs]);
  __syncthreads();

  int buf = 0;
  for (int ks = 0; ks < 16; ++ks) {
    if (ks < 15) {
      int k0 = (ks + 1) * 32;
      int nb = buf ^ 1;
#pragma unroll
      for (int i = 0; i < 4; ++i)
        GLOAD_LDS16(gA0 + (size_t)(64 * i) * HID + k0, &As[nb][i * 2048 + wofs]);
      GLOAD_LDS16(gB0 + k0, &Bq[nb][wofs]);
    }
    short8 a[4], bb[4];
#pragma unroll
    for (int mt = 0; mt < 4; ++mt) {
      int R = w * 64 + mt * 16 + lane_r;
      a[mt] = *(const short8*)&As[buf][R * 32 + (lane_g ^ rq) * 8];
    }
#pragma unroll
    for (int nt = 0; nt < 4; ++nt) {
      int R = nt * 16 + lane_r;
      bb[nt] = *(const short8*)&Bq[buf][R * 32 + (lane_g ^ rq) * 8];
    }
#pragma unroll
    for (int mt = 0; mt < 4; ++mt)
#pragma unroll
      for (int nt = 0; nt < 4; ++nt)
        acc[mt][nt] = __builtin_amdgcn_mfma_f32_16x16x32_bf16(a[mt], bb[nt], acc[mt][nt], 0, 0, 0);
    if (ks < 15) __syncthreads();
    buf ^= 1;
  }

  float colsq[4] = {0.f, 0.f, 0.f, 0.f};
#pragma unroll
  for (int mt = 0; mt < 4; ++mt)
#pragma unroll
    for (int r = 0; r < 4; ++r) {
      int o = w * 64 + mt * 16 + lane_g * 4 + r;
      float bo = bout[o];
#pragma unroll
      for (int nt = 0; nt < 4; ++nt) {
        float t = acc[mt][nt][r] + bo;
        acc[mt][nt][r] = t;
        colsq[nt] += t * t;
      }
    }
#pragma unroll
  for (int nt = 0; nt < 4; ++nt) {
    colsq[nt] += __shfl_xor(colsq[nt], 16);
    colsq[nt] += __shfl_xor(colsq[nt], 32);
  }
  __shared__ float cred[4][64];
  if (l < 16) {
#pragma unroll
    for (int nt = 0; nt < 4; ++nt) cred[w][nt * 16 + l] = colsq[nt];
  }
  __syncthreads();
  float inv[4];
#pragma unroll
  for (int nt = 0; nt < 4; ++nt) {
    int col = nt * 16 + lane_r;
    float s = cred[0][col] + cred[1][col] + cred[2][col] + cred[3][col];
    float nrm = sqrtf(s);
    inv[nt] = 16.0f / fmaxf(nrm, 1e-12f);
  }
  float* ob = out + (size_t)b * 256 * NPIX;
#pragma unroll
  for (int mt = 0; mt < 4; ++mt)
#pragma unroll
    for (int r = 0; r < 4; ++r) {
      int o = w * 64 + mt * 16 + lane_g * 4 + r;
      float g = g2[o];
#pragma unroll
      for (int nt = 0; nt < 4; ++nt) {
        int p = n0 + nt * 16 + lane_r;
        ob[(size_t)o * NPIX + p] = acc[mt][nt][r] * inv[nt] * g;
      }
    }
}

extern "C" void kernel_launch(void* const* d_in, const int* in_sizes, int n_in,
                              void* d_out, int out_size, void* d_ws, size_t ws_size,
                              hipStream_t stream) {
  const float* x    = (const float*)d_in[0];
  const float* g1   = (const float*)d_in[1];
  const float* wqkv = (const float*)d_in[2];
  const float* wout = (const float*)d_in[3];
  const float* bout = (const float*)d_in[4];
  const float* g2   = (const float*)d_in[5];
  float* out = (float*)d_out;
  char* ws = (char*)d_ws;

  // workspace layout (bytes)
  ushortT* xnT   = (ushortT*)(ws);                       // 16*4096*256*2  = 33554432
  ushortT* kv    = (ushortT*)(ws + 33554432);            // 16*1024*4096*2 = 134217728
  ushortT* qT    = (ushortT*)(ws + 167772160);           // 16*4096*512*2  = 67108864
  ushortT* ctx   = (ushortT*)(ws + 234881024);           // 16*8*64*64*2   = 131072
  ushortT* weff  = (ushortT*)(ws + 235012096);           // 16*256*512*2   = 4194304
  ushortT* wqkvb = (ushortT*)(ws + 239206400);           // 1536*256*2     = 786432
  ushortT* woutb = (ushortT*)(ws + 239992832);           // 256*512*2      = 262144
  float*   ctxp  = (float*)(ws);                         // 8MB, reuses dead xnT region

  hipLaunchKernelGGL(k_convw,  dim3(1536), dim3(256), 0, stream, wqkv, wout, wqkvb, woutb);
  hipLaunchKernelGGL(k_rms1,   dim3(256),  dim3(256), 0, stream, x, g1, xnT);
  hipLaunchKernelGGL(k_qkv,    dim3(32, 12, 16), dim3(256), 0, stream, wqkvb, xnT, qT, kv);
  hipLaunchKernelGGL(k_ksm,    dim3(8192), dim3(256), 0, stream, kv);
  hipLaunchKernelGGL(k_ctx,    dim3(512),  dim3(256), 0, stream, kv, ctxp);
  hipLaunchKernelGGL(k_ctxsum, dim3(2048), dim3(256), 0, stream, ctxp, ctx);
  hipLaunchKernelGGL(k_weff,   dim3(128),  dim3(256), 0, stream, woutb, ctx, weff);
  hipLaunchKernelGGL(k_out,    dim3(64, 16), dim3(256), 0, stream, weff, qT, bout, g2, out);
}

// Round 7
// 242.738 us; speedup vs baseline: 1.7853x; 1.0162x over previous
//
#include <hip/hip_runtime.h>

typedef unsigned short ushortT;
typedef unsigned short ushort8 __attribute__((ext_vector_type(8)));
typedef unsigned short ushort4v __attribute__((ext_vector_type(4)));
typedef short short8 __attribute__((ext_vector_type(8)));
typedef float floatx4 __attribute__((ext_vector_type(4)));

#define DEVINL __device__ __forceinline__

static DEVINL ushortT f2bf(float f) {
  union { float f; unsigned u; } v; v.f = f;
  unsigned u = v.u + 0x7FFFu + ((v.u >> 16) & 1u);
  return (ushortT)(u >> 16);
}
static DEVINL float bf2f(ushortT h) {
  union { unsigned u; float f; } v; v.u = ((unsigned)h) << 16;
  return v.f;
}

#define GLOAD_LDS16(g, s) __builtin_amdgcn_global_load_lds( \
    (const __attribute__((address_space(1))) void*)(g),     \
    (__attribute__((address_space(3))) void*)(s), 16, 0, 0)

// dims: B=16, C=256, HID=512, NH=8, DH=64, N=4096
#define NB 16
#define CIN 256
#define HID 512
#define NPIX 4096

// ---------------- K0: convert weights to bf16 ----------------
__global__ __launch_bounds__(256) void k_convw(const float* __restrict__ wqkv,
                                               const float* __restrict__ wout,
                                               ushortT* __restrict__ wqkvb,
                                               ushortT* __restrict__ woutb) {
  int i = blockIdx.x * 256 + threadIdx.x;
  if (i < 1536 * 256) wqkvb[i] = f2bf(wqkv[i]);
  if (i < 256 * 512)  woutb[i] = f2bf(wout[i]);
}

// ---------------- K1: rmsnorm over channels, write xn transposed [b][p][c] bf16 ----------------
__global__ __launch_bounds__(256) void k_rms1(const float* __restrict__ x,
                                              const float* __restrict__ g1,
                                              ushortT* __restrict__ xnT) {
  int pid = blockIdx.x * 256 + threadIdx.x;   // 0..65535
  int b = pid >> 12, p = pid & 4095;
  const float* xb = x + (size_t)b * CIN * NPIX + p;
  float ss = 0.f;
  for (int c = 0; c < CIN; ++c) { float v = xb[(size_t)c * NPIX]; ss += v * v; }
  float nrm = sqrtf(ss);
  float sc = 16.0f / fmaxf(nrm, 1e-12f);
  ushortT* dst = xnT + (size_t)pid * CIN;
  for (int c0 = 0; c0 < CIN; c0 += 8) {
    ushort8 pack;
#pragma unroll
    for (int j = 0; j < 8; ++j) {
      int c = c0 + j;
      pack[j] = f2bf(xb[(size_t)c * NPIX] * sc * g1[c]);
    }
    *(ushort8*)(dst + c0) = pack;
  }
}

// ---------------- K2: qkv GEMM, BK=64 dbuf staging, swizzled LDS ----------------
// A=WqkvB [o][c] K-major, B=xnT [p][c] K-major. Tile 128x128, 4 waves (2x2).
// LDS rows 128B (64 bf16 = 8 chunks of 16B); physical chunk = logical ^ (row&7).
// Source pre-swizzled (global_load_lds dest is linear; both-sides-or-neither).
// q (o<512): fused softmax over d (wave's 64 rows = one head) -> qT[b][p][o]
// k,v (o>=512): raw GEMM output -> kv[b][o-512][p]  (r3-proven scalar-store epilogue)
__global__ __launch_bounds__(256) void k_qkv(const ushortT* __restrict__ wq,
                                             const ushortT* __restrict__ xnT,
                                             ushortT* __restrict__ qT,
                                             ushortT* __restrict__ kv) {
  int bn = blockIdx.x;       // 0..31  (p tile of 128)
  int bm = blockIdx.y;       // 0..11  (o tile of 128)
  int b  = blockIdx.z;
  int tid = threadIdx.x;
  int w = tid >> 6, l = tid & 63;
  int wm = w >> 1, wn = w & 1;
  int lane_r = l & 15, lane_g = l >> 4;
  int m0 = bm * 128, n0 = bn * 128;

  __shared__ __align__(16) ushortT smem[2][2][128 * 64];   // [buf][A/B], 64KB

  const ushortT* xb = xnT + (size_t)b * NPIX * CIN;

  int srow = tid >> 3;                            // 0..31 (row within 32-row group)
  int scol = ((tid & 7) ^ (srow & 7)) * 8;        // pre-swizzled source col
  const ushortT* gA0 = wq + (size_t)(m0 + srow) * CIN + scol;
  const ushortT* gB0 = xb + (size_t)(n0 + srow) * CIN + scol;
  int ldsrow = w * 8;                             // wave-uniform base row per instr

  floatx4 acc[4][4];
#pragma unroll
  for (int i = 0; i < 4; i++)
#pragma unroll
    for (int j = 0; j < 4; j++) acc[i][j] = (floatx4)0.f;

  // prologue: stage k-step 0 into buf 0
#pragma unroll
  for (int i = 0; i < 4; ++i)
    GLOAD_LDS16(gA0 + (size_t)(32 * i) * CIN, &smem[0][0][(ldsrow + 32 * i) * 64]);
#pragma unroll
  for (int i = 0; i < 4; ++i)
    GLOAD_LDS16(gB0 + (size_t)(32 * i) * CIN, &smem[0][1][(ldsrow + 32 * i) * 64]);
  __syncthreads();

  int buf = 0;
  for (int ks = 0; ks < 4; ++ks) {
    if (ks < 3) {
      int k0 = (ks + 1) * 64;
      int nb = buf ^ 1;
#pragma unroll
      for (int i = 0; i < 4; ++i)
        GLOAD_LDS16(gA0 + (size_t)(32 * i) * CIN + k0, &smem[nb][0][(ldsrow + 32 * i) * 64]);
#pragma unroll
      for (int i = 0; i < 4; ++i)
        GLOAD_LDS16(gB0 + (size_t)(32 * i) * CIN + k0, &smem[nb][1][(ldsrow + 32 * i) * 64]);
    }
#pragma unroll
    for (int kk = 0; kk < 2; ++kk) {
      int phys = (kk * 4 + lane_g) ^ (lane_r & 7);
      short8 a[4], bb[4];
#pragma unroll
      for (int mt = 0; mt < 4; ++mt) {
        int R = wm * 64 + mt * 16 + lane_r;
        a[mt] = *(const short8*)&smem[buf][0][R * 64 + phys * 8];
      }
#pragma unroll
      for (int nt = 0; nt < 4; ++nt) {
        int R = wn * 64 + nt * 16 + lane_r;
        bb[nt] = *(const short8*)&smem[buf][1][R * 64 + phys * 8];
      }
#pragma unroll
      for (int mt = 0; mt < 4; ++mt)
#pragma unroll
        for (int nt = 0; nt < 4; ++nt)
          acc[mt][nt] = __builtin_amdgcn_mfma_f32_16x16x32_bf16(a[mt], bb[nt], acc[mt][nt], 0, 0, 0);
    }
    if (ks < 3) __syncthreads();
    buf ^= 1;
  }

  int m0w = m0 + wm * 64, n0w = n0 + wn * 64;

  if (m0w < 512) {
    // ---- fused q softmax over d: wave's 64 rows are exactly one head ----
    float inv[4];
#pragma unroll
    for (int nt = 0; nt < 4; ++nt) {
      float mx = -1e30f;
#pragma unroll
      for (int mt = 0; mt < 4; ++mt)
#pragma unroll
        for (int r = 0; r < 4; ++r) mx = fmaxf(mx, acc[mt][nt][r]);
      mx = fmaxf(mx, __shfl_xor(mx, 16));
      mx = fmaxf(mx, __shfl_xor(mx, 32));
      float s = 0.f;
#pragma unroll
      for (int mt = 0; mt < 4; ++mt)
#pragma unroll
        for (int r = 0; r < 4; ++r) {
          float e = __expf(acc[mt][nt][r] - mx);
          acc[mt][nt][r] = e;
          s += e;
        }
      s += __shfl_xor(s, 16);
      s += __shfl_xor(s, 32);
      inv[nt] = 0.125f / s;    // SCALE = 1/8 folded in
    }
    ushortT* qb = qT + (size_t)b * NPIX * HID;
#pragma unroll
    for (int mt = 0; mt < 4; ++mt) {
      int o = m0w + mt * 16 + lane_g * 4;
#pragma unroll
      for (int nt = 0; nt < 4; ++nt) {
        int p = n0w + nt * 16 + lane_r;
        ushort4v pk;
#pragma unroll
        for (int r = 0; r < 4; ++r) pk[r] = f2bf(acc[mt][nt][r] * inv[nt]);
        *(ushort4v*)(qb + (size_t)p * HID + o) = pk;
      }
    }
  } else {          // k,v raw -> kv[ch][p], scalar stores (r3-proven path)
    ushortT* kvb = kv + (size_t)b * 1024 * NPIX;
    int mo = m0w - 512;
#pragma unroll
    for (int mt = 0; mt < 4; ++mt)
#pragma unroll
      for (int nt = 0; nt < 4; ++nt) {
        int p = n0w + nt * 16 + lane_r;
#pragma unroll
        for (int r = 0; r < 4; ++r) {
          int ch = mo + mt * 16 + lane_g * 4 + r;
          kvb[(size_t)ch * NPIX + p] = f2bf(acc[mt][nt][r]);
        }
      }
  }
}

// ---------------- K3a: k softmax over n (4096), in place, vectorized loads ----------------
__global__ __launch_bounds__(256) void k_ksm(ushortT* __restrict__ kv) {
  int row = blockIdx.x;                // 0..8191
  int b = row >> 9, ch = row & 511;
  ushortT* ptr = kv + (size_t)(b * 1024 + ch) * NPIX;
  int tid = threadIdx.x;
  int w = tid >> 6, l = tid & 63;
  // each thread owns 16 contiguous elements [tid*16, tid*16+16)
  ushort8 r0 = *(ushort8*)(ptr + tid * 16);
  ushort8 r1 = *(ushort8*)(ptr + tid * 16 + 8);
  float v[16];
  float mx = -1e30f;
#pragma unroll
  for (int j = 0; j < 8; ++j) { v[j] = bf2f(r0[j]); v[8 + j] = bf2f(r1[j]); }
#pragma unroll
  for (int j = 0; j < 16; ++j) mx = fmaxf(mx, v[j]);
  for (int off = 32; off; off >>= 1) mx = fmaxf(mx, __shfl_xor(mx, off));
  __shared__ float smax[4], ssum[4];
  if (l == 0) smax[w] = mx;
  __syncthreads();
  mx = fmaxf(fmaxf(smax[0], smax[1]), fmaxf(smax[2], smax[3]));
  float s = 0.f;
#pragma unroll
  for (int j = 0; j < 16; ++j) { v[j] = __expf(v[j] - mx); s += v[j]; }
  for (int off = 32; off; off >>= 1) s += __shfl_xor(s, off);
  if (l == 0) ssum[w] = s;
  __syncthreads();
  s = ssum[0] + ssum[1] + ssum[2] + ssum[3];
  float inv = 1.0f / s;
  ushort8 o0, o1;
#pragma unroll
  for (int j = 0; j < 8; ++j) { o0[j] = f2bf(v[j] * inv); o1[j] = f2bf(v[8 + j] * inv); }
  *(ushort8*)(ptr + tid * 16) = o0;
  *(ushort8*)(ptr + tid * 16 + 8) = o1;
}

// ---------------- K4: partial context over n-segment, staged LDS (r3-proven) ----------------
__global__ __launch_bounds__(256) void k_ctx(const ushortT* __restrict__ kv,
                                             float* __restrict__ ctxp) {
  int blk = blockIdx.x;   // 0..511
  int bh = blk >> 2, ns = blk & 3;
  int b = bh >> 3, h = bh & 7;
  int tid = threadIdx.x, w = tid >> 6, l = tid & 63;
  int lane_r = l & 15, lane_g = l >> 4;
  const ushortT* kb = kv + ((size_t)b * 1024 + h * 64) * NPIX + ns * 1024;
  const ushortT* vb = kv + ((size_t)b * 1024 + 512 + h * 64) * NPIX + ns * 1024;

  __shared__ __align__(16) ushortT smem[4][64 * 128];   // 64KB: [0..1]=K bufs, [2..3]=V bufs

  int srow = tid >> 4;                    // 0..15
  int soff = ((tid & 15) ^ srow) * 8;     // pre-swizzled source col (elems)
  int wofs = w * 512;                     // per-wave LDS base within a 4KB op
  int cbase = (w * 4 + lane_g);           // this wave's logical chunk id

  floatx4 acc[4][4];
#pragma unroll
  for (int i = 0; i < 4; i++)
#pragma unroll
    for (int j = 0; j < 4; j++) acc[i][j] = (floatx4)0.f;

  // prologue stage step 0 into buf 0
#pragma unroll
  for (int i = 0; i < 4; ++i)
    GLOAD_LDS16(kb + (size_t)(srow + 16 * i) * NPIX + soff, &smem[0][i * 2048 + wofs]);
#pragma unroll
  for (int i = 0; i < 4; ++i)
    GLOAD_LDS16(vb + (size_t)(srow + 16 * i) * NPIX + soff, &smem[2][i * 2048 + wofs]);
  __syncthreads();

  int buf = 0;
  for (int st = 0; st < 8; ++st) {
    if (st < 7) {
      int nb0 = (st + 1) * 128;
      int nb = buf ^ 1;
#pragma unroll
      for (int i = 0; i < 4; ++i)
        GLOAD_LDS16(kb + (size_t)(srow + 16 * i) * NPIX + nb0 + soff, &smem[nb][i * 2048 + wofs]);
#pragma unroll
      for (int i = 0; i < 4; ++i)
        GLOAD_LDS16(vb + (size_t)(srow + 16 * i) * NPIX + nb0 + soff, &smem[2 + nb][i * 2048 + wofs]);
    }
    short8 a[4], bb[4];
#pragma unroll
    for (int mt = 0; mt < 4; ++mt) {
      int R = mt * 16 + lane_r;
      a[mt] = *(const short8*)&smem[buf][R * 128 + (cbase ^ lane_r) * 8];
    }
#pragma unroll
    for (int nt = 0; nt < 4; ++nt) {
      int R = nt * 16 + lane_r;
      bb[nt] = *(const short8*)&smem[2 + buf][R * 128 + (cbase ^ lane_r) * 8];
    }
#pragma unroll
    for (int mt = 0; mt < 4; ++mt)
#pragma unroll
      for (int nt = 0; nt < 4; ++nt)
        acc[mt][nt] = __builtin_amdgcn_mfma_f32_16x16x32_bf16(a[mt], bb[nt], acc[mt][nt], 0, 0, 0);
    if (st < 7) __syncthreads();
    buf ^= 1;
  }

  // cross-wave reduction, aliasing the (now dead) staging LDS
  __syncthreads();
  float* red = (float*)&smem[0][0];       // [4][64][64] f32 = 64KB
#pragma unroll
  for (int mt = 0; mt < 4; ++mt)
#pragma unroll
    for (int nt = 0; nt < 4; ++nt)
#pragma unroll
      for (int r = 0; r < 4; ++r)
        red[(w * 64 + mt * 16 + lane_g * 4 + r) * 64 + nt * 16 + lane_r] = acc[mt][nt][r];
  __syncthreads();
  float* cb = ctxp + (size_t)blk * 4096;
  int base = tid * 16;
#pragma unroll
  for (int j = 0; j < 16; ++j) {
    int idx = base + j;
    cb[idx] = red[idx] + red[4096 + idx] + red[8192 + idx] + red[12288 + idx];
  }
}

// ---------------- K4b: sum 4 n-segment partials -> ctx bf16 ----------------
__global__ __launch_bounds__(256) void k_ctxsum(const float* __restrict__ ctxp,
                                                ushortT* __restrict__ ctx) {
  int i = blockIdx.x * 256 + threadIdx.x;   // < 524288
  int bh = i >> 12, j = i & 4095;
  const float* p = ctxp + (size_t)bh * 4 * 4096 + j;
  ctx[i] = f2bf(p[0] + p[4096] + p[8192] + p[12288]);
}

// ---------------- K5: Weff[b][o][h*64+d] = sum_e Wout[o][h*64+e] * ctx[b,h,d,e] ----------------
__global__ __launch_bounds__(256) void k_weff(const ushortT* __restrict__ woutb,
                                              const ushortT* __restrict__ ctx,
                                              ushortT* __restrict__ weff) {
  int bh = blockIdx.x; int b = bh >> 3, h = bh & 7;
  int tid = threadIdx.x, w = tid >> 6, l = tid & 63;
  int lane_r = l & 15, lane_g = l >> 4;
  const ushortT* cb = ctx + (size_t)bh * 64 * 64;

  floatx4 acc[4][4];
#pragma unroll
  for (int i = 0; i < 4; i++)
#pragma unroll
    for (int j = 0; j < 4; j++) acc[i][j] = (floatx4)0.f;

#pragma unroll
  for (int ks = 0; ks < 2; ++ks) {
    int k0 = ks * 32 + lane_g * 8;
    short8 a[4], bb[4];
#pragma unroll
    for (int mt = 0; mt < 4; ++mt)
      a[mt] = *(const short8*)(woutb + (size_t)(w * 64 + mt * 16 + lane_r) * HID + h * 64 + k0);
#pragma unroll
    for (int nt = 0; nt < 4; ++nt)
      bb[nt] = *(const short8*)(cb + (size_t)(nt * 16 + lane_r) * 64 + k0);
#pragma unroll
    for (int mt = 0; mt < 4; ++mt)
#pragma unroll
      for (int nt = 0; nt < 4; ++nt)
        acc[mt][nt] = __builtin_amdgcn_mfma_f32_16x16x32_bf16(a[mt], bb[nt], acc[mt][nt], 0, 0, 0);
  }
  ushortT* wb = weff + (size_t)b * 256 * 512;
#pragma unroll
  for (int mt = 0; mt < 4; ++mt)
#pragma unroll
    for (int nt = 0; nt < 4; ++nt)
#pragma unroll
      for (int r = 0; r < 4; ++r) {
        int o = w * 64 + mt * 16 + lane_g * 4 + r;
        int d = nt * 16 + lane_r;
        wb[(size_t)o * 512 + h * 64 + d] = f2bf(acc[mt][nt][r]);
      }
}

// ---------------- K6: out = Weff[b] @ qT[b]^T, staged LDS, + bias, fused rmsnorm ----------------
__global__ __launch_bounds__(256) void k_out(const ushortT* __restrict__ weff,
                                             const ushortT* __restrict__ qT,
                                             const float* __restrict__ bout,
                                             const float* __restrict__ g2,
                                             float* __restrict__ out) {
  int bn = blockIdx.x;   // 0..63 (p tile of 64)
  int b  = blockIdx.y;
  int tid = threadIdx.x, w = tid >> 6, l = tid & 63;
  int lane_r = l & 15, lane_g = l >> 4;
  const ushortT* wb = weff + (size_t)b * 256 * 512;
  const ushortT* qb = qT + (size_t)b * NPIX * HID;
  int n0 = bn * 64;

  __shared__ ushortT As[2][256 * 32];   // 16KB per buf
  __shared__ ushortT Bq[2][64 * 32];    // 4KB per buf

  int srow = tid >> 2;                                // 0..63
  int scol = ((tid & 3) ^ ((tid >> 3) & 3)) * 8;
  const ushortT* gA0 = wb + (size_t)srow * HID + scol;
  const ushortT* gB0 = qb + (size_t)(n0 + srow) * HID + scol;
  int wofs = w * 512;
  int rq = (lane_r >> 1) & 3;

  floatx4 acc[4][4];
#pragma unroll
  for (int i = 0; i < 4; i++)
#pragma unroll
    for (int j = 0; j < 4; j++) acc[i][j] = (floatx4)0.f;

  // prologue
#pragma unroll
  for (int i = 0; i < 4; ++i)
    GLOAD_LDS16(gA0 + (size_t)(64 * i) * HID, &As[0][i * 2048 + wofs]);
  GLOAD_LDS16(gB0, &Bq[0][wofs]);
  __syncthreads();

  int buf = 0;
  for (int ks = 0; ks < 16; ++ks) {
    if (ks < 15) {
      int k0 = (ks + 1) * 32;
      int nb = buf ^ 1;
#pragma unroll
      for (int i = 0; i < 4; ++i)
        GLOAD_LDS16(gA0 + (size_t)(64 * i) * HID + k0, &As[nb][i * 2048 + wofs]);
      GLOAD_LDS16(gB0 + k0, &Bq[nb][wofs]);
    }
    short8 a[4], bb[4];
#pragma unroll
    for (int mt = 0; mt < 4; ++mt) {
      int R = w * 64 + mt * 16 + lane_r;
      a[mt] = *(const short8*)&As[buf][R * 32 + (lane_g ^ rq) * 8];
    }
#pragma unroll
    for (int nt = 0; nt < 4; ++nt) {
      int R = nt * 16 + lane_r;
      bb[nt] = *(const short8*)&Bq[buf][R * 32 + (lane_g ^ rq) * 8];
    }
#pragma unroll
    for (int mt = 0; mt < 4; ++mt)
#pragma unroll
      for (int nt = 0; nt < 4; ++nt)
        acc[mt][nt] = __builtin_amdgcn_mfma_f32_16x16x32_bf16(a[mt], bb[nt], acc[mt][nt], 0, 0, 0);
    if (ks < 15) __syncthreads();
    buf ^= 1;
  }

  float colsq[4] = {0.f, 0.f, 0.f, 0.f};
#pragma unroll
  for (int mt = 0; mt < 4; ++mt)
#pragma unroll
    for (int r = 0; r < 4; ++r) {
      int o = w * 64 + mt * 16 + lane_g * 4 + r;
      float bo = bout[o];
#pragma unroll
      for (int nt = 0; nt < 4; ++nt) {
        float t = acc[mt][nt][r] + bo;
        acc[mt][nt][r] = t;
        colsq[nt] += t * t;
      }
    }
#pragma unroll
  for (int nt = 0; nt < 4; ++nt) {
    colsq[nt] += __shfl_xor(colsq[nt], 16);
    colsq[nt] += __shfl_xor(colsq[nt], 32);
  }
  __shared__ float cred[4][64];
  if (l < 16) {
#pragma unroll
    for (int nt = 0; nt < 4; ++nt) cred[w][nt * 16 + l] = colsq[nt];
  }
  __syncthreads();
  float inv[4];
#pragma unroll
  for (int nt = 0; nt < 4; ++nt) {
    int col = nt * 16 + lane_r;
    float s = cred[0][col] + cred[1][col] + cred[2][col] + cred[3][col];
    float nrm = sqrtf(s);
    inv[nt] = 16.0f / fmaxf(nrm, 1e-12f);
  }
  float* ob = out + (size_t)b * 256 * NPIX;
#pragma unroll
  for (int mt = 0; mt < 4; ++mt)
#pragma unroll
    for (int r = 0; r < 4; ++r) {
      int o = w * 64 + mt * 16 + lane_g * 4 + r;
      float g = g2[o];
#pragma unroll
      for (int nt = 0; nt < 4; ++nt) {
        int p = n0 + nt * 16 + lane_r;
        ob[(size_t)o * NPIX + p] = acc[mt][nt][r] * inv[nt] * g;
      }
    }
}

extern "C" void kernel_launch(void* const* d_in, const int* in_sizes, int n_in,
                              void* d_out, int out_size, void* d_ws, size_t ws_size,
                              hipStream_t stream) {
  const float* x    = (const float*)d_in[0];
  const float* g1   = (const float*)d_in[1];
  const float* wqkv = (const float*)d_in[2];
  const float* wout = (const float*)d_in[3];
  const float* bout = (const float*)d_in[4];
  const float* g2   = (const float*)d_in[5];
  float* out = (float*)d_out;
  char* ws = (char*)d_ws;

  // workspace layout (bytes)
  ushortT* xnT   = (ushortT*)(ws);                       // 16*4096*256*2  = 33554432
  ushortT* kv    = (ushortT*)(ws + 33554432);            // 16*1024*4096*2 = 134217728
  ushortT* qT    = (ushortT*)(ws + 167772160);           // 16*4096*512*2  = 67108864
  ushortT* ctx   = (ushortT*)(ws + 234881024);           // 16*8*64*64*2   = 131072
  ushortT* weff  = (ushortT*)(ws + 235012096);           // 16*256*512*2   = 4194304
  ushortT* wqkvb = (ushortT*)(ws + 239206400);           // 1536*256*2     = 786432
  ushortT* woutb = (ushortT*)(ws + 239992832);           // 256*512*2      = 262144
  float*   ctxp  = (float*)(ws);                         // 8MB, reuses dead xnT region

  hipLaunchKernelGGL(k_convw,  dim3(1536), dim3(256), 0, stream, wqkv, wout, wqkvb, woutb);
  hipLaunchKernelGGL(k_rms1,   dim3(256),  dim3(256), 0, stream, x, g1, xnT);
  hipLaunchKernelGGL(k_qkv,    dim3(32, 12, 16), dim3(256), 0, stream, wqkvb, xnT, qT, kv);
  hipLaunchKernelGGL(k_ksm,    dim3(8192), dim3(256), 0, stream, kv);
  hipLaunchKernelGGL(k_ctx,    dim3(512),  dim3(256), 0, stream, kv, ctxp);
  hipLaunchKernelGGL(k_ctxsum, dim3(2048), dim3(256), 0, stream, ctxp, ctx);
  hipLaunchKernelGGL(k_weff,   dim3(128),  dim3(256), 0, stream, woutb, ctx, weff);
  hipLaunchKernelGGL(k_out,    dim3(64, 16), dim3(256), 0, stream, weff, qT, bout, g2, out);
}